// Round 1
// baseline (3287.524 us; speedup 1.0000x reference)
//
#include <hip/hip_runtime.h>
#include <hip/hip_bf16.h>
#include <math.h>

// ---------------------------------------------------------------------------
// Dims (fixed per reference)
// ---------------------------------------------------------------------------
#define BATCH   16384
#define D_IN    1024
#define H1_DIM  512
#define H2_DIM  256
#define H3_DIM  128
#define D_CBP   2048
#define H_C     1024
#define CLASSES 10
#define SLOPE   0.2f

// ---------------------------------------------------------------------------
// Generic tiled fp32 GEMM: C[M,N] = lrelu(A[M,K] @ W[K,N] + bias[N])
// BM=BN=64, BK=16, 256 threads, 4x4 micro-tile per thread.
// M,N multiples of 64; K multiple of 16 (true for all call sites).
// ---------------------------------------------------------------------------
#define BM 64
#define BN 64
#define BK 16

__global__ __launch_bounds__(256) void gemm_bias_lrelu(
    const float* __restrict__ A, const float* __restrict__ W,
    const float* __restrict__ bias, float* __restrict__ C,
    int M, int N, int K)
{
  __shared__ float As[BK][BM];   // [k][m]  (transposed for broadcast float4 reads)
  __shared__ float Bs[BK][BN];   // [k][n]

  const int tid = threadIdx.x;
  const int tx  = tid & 15;      // n-direction (4 cols each)
  const int ty  = tid >> 4;      // m-direction (4 rows each)
  const int m0  = blockIdx.y * BM;
  const int n0  = blockIdx.x * BN;

  // staging assignment
  const int am = tid >> 2;            // 0..63  (tile row)
  const int ak = (tid & 3) << 2;      // 0,4,8,12
  const int bk = tid >> 4;            // 0..15
  const int bn = (tid & 15) << 2;     // 0..60

  const float* Ag = A + (size_t)(m0 + am) * K + ak;
  const float* Wg = W + (size_t)bk * N + n0 + bn;

  float acc[4][4] = {{0.f,0.f,0.f,0.f},{0.f,0.f,0.f,0.f},
                     {0.f,0.f,0.f,0.f},{0.f,0.f,0.f,0.f}};

  for (int k0 = 0; k0 < K; k0 += BK) {
    const float4 av = *(const float4*)(Ag + k0);
    const float4 bv = *(const float4*)(Wg + (size_t)k0 * N);
    __syncthreads();               // protect previous iteration's reads
    As[ak + 0][am] = av.x;
    As[ak + 1][am] = av.y;
    As[ak + 2][am] = av.z;
    As[ak + 3][am] = av.w;
    *(float4*)&Bs[bk][bn] = bv;
    __syncthreads();
#pragma unroll
    for (int kk = 0; kk < BK; ++kk) {
      const float4 a4 = *(const float4*)&As[kk][ty << 2];
      const float4 b4 = *(const float4*)&Bs[kk][tx << 2];
      acc[0][0] += a4.x*b4.x; acc[0][1] += a4.x*b4.y; acc[0][2] += a4.x*b4.z; acc[0][3] += a4.x*b4.w;
      acc[1][0] += a4.y*b4.x; acc[1][1] += a4.y*b4.y; acc[1][2] += a4.y*b4.z; acc[1][3] += a4.y*b4.w;
      acc[2][0] += a4.z*b4.x; acc[2][1] += a4.z*b4.y; acc[2][2] += a4.z*b4.z; acc[2][3] += a4.z*b4.w;
      acc[3][0] += a4.w*b4.x; acc[3][1] += a4.w*b4.y; acc[3][2] += a4.w*b4.z; acc[3][3] += a4.w*b4.w;
    }
  }

  const float4 bb4 = *(const float4*)(bias + n0 + (tx << 2));
#pragma unroll
  for (int i = 0; i < 4; ++i) {
    float4 v;
    v.x = acc[i][0] + bb4.x;
    v.y = acc[i][1] + bb4.y;
    v.z = acc[i][2] + bb4.z;
    v.w = acc[i][3] + bb4.w;
    v.x = v.x >= 0.f ? v.x : SLOPE * v.x;
    v.y = v.y >= 0.f ? v.y : SLOPE * v.y;
    v.z = v.z >= 0.f ? v.z : SLOPE * v.z;
    v.w = v.w >= 0.f ? v.w : SLOPE * v.w;
    *(float4*)(C + (size_t)(m0 + (ty << 2) + i) * N + n0 + (tx << 2)) = v;
  }
}

// ---------------------------------------------------------------------------
// Compact bilinear pooling: count-sketch outer-product scatter.
// cbp[b][(h1[i]+h2[j]) & 2047] += s1[i]*ex[b,i] * s2[j]*ec[b,j]
// One 256-thread block per row; 2048 bins in LDS with float atomics.
// (Equivalent to irfft(rfft(sk1)*rfft(sk2)) because sk1/sk2 are sparse.)
// ---------------------------------------------------------------------------
__global__ __launch_bounds__(256) void cbp_kernel(
    const float* __restrict__ E3,   // [2*BATCH, 128]: rows 0..B-1 = ex, B.. = ec
    const int*   __restrict__ h1, const float* __restrict__ s1,
    const int*   __restrict__ h2, const float* __restrict__ s2,
    float* __restrict__ cbp)        // [BATCH, 2048]
{
  __shared__ float bins[D_CBP];
  __shared__ float a[H3_DIM], bb[H3_DIM];
  __shared__ int   ha[H3_DIM], hb[H3_DIM];

  const int b = blockIdx.x;
  const int t = threadIdx.x;

  for (int k = t; k < D_CBP; k += 256) bins[k] = 0.f;
  if (t < H3_DIM) {
    a[t]  = E3[(size_t)b * H3_DIM + t] * s1[t];
    ha[t] = h1[t];
  } else {
    const int j = t - H3_DIM;
    bb[j] = E3[(size_t)(BATCH + b) * H3_DIM + j] * s2[j];
    hb[j] = h2[j];
  }
  __syncthreads();

  const int   j  = t & 127;
  const float bj = bb[j];
  const int   hj = hb[j];
  const int   i0 = t >> 7;           // 0 or 1
#pragma unroll 8
  for (int i = i0; i < H3_DIM; i += 2) {
    atomicAdd(&bins[(ha[i] + hj) & (D_CBP - 1)], a[i] * bj);
  }
  __syncthreads();

  float* dst = cbp + (size_t)b * D_CBP;
  for (int k = t; k < D_CBP; k += 256) dst[k] = bins[k];
}

// ---------------------------------------------------------------------------
// Head: logits = Z[B,1024] @ Wc2[1024,10] + bc2; out = softmax(logits).
// One wave per row (4 rows / 256-thread block); shuffle reduction.
// ---------------------------------------------------------------------------
__global__ __launch_bounds__(256) void head_softmax(
    const float* __restrict__ Z, const float* __restrict__ Wc2,
    const float* __restrict__ bc2, float* __restrict__ out)
{
  const int row  = blockIdx.x * 4 + (threadIdx.x >> 6);
  const int lane = threadIdx.x & 63;

  float acc[CLASSES];
#pragma unroll
  for (int c = 0; c < CLASSES; ++c) acc[c] = 0.f;

  const float* z = Z + (size_t)row * H_C;
  for (int k = lane; k < H_C; k += 64) {
    const float zv = z[k];
    const float* w = Wc2 + (size_t)k * CLASSES;
#pragma unroll
    for (int c = 0; c < CLASSES; ++c) acc[c] += zv * w[c];
  }
#pragma unroll
  for (int c = 0; c < CLASSES; ++c) {
#pragma unroll
    for (int off = 32; off > 0; off >>= 1)
      acc[c] += __shfl_down(acc[c], off);
  }
  if (lane == 0) {
    float l[CLASSES], mx = -1e30f;
#pragma unroll
    for (int c = 0; c < CLASSES; ++c) { l[c] = acc[c] + bc2[c]; mx = fmaxf(mx, l[c]); }
    float s = 0.f;
#pragma unroll
    for (int c = 0; c < CLASSES; ++c) { l[c] = __expf(l[c] - mx); s += l[c]; }
    const float inv = 1.f / s;
#pragma unroll
    for (int c = 0; c < CLASSES; ++c) out[(size_t)row * CLASSES + c] = l[c] * inv;
  }
}

// ---------------------------------------------------------------------------
// Launcher. Workspace layout (192 MiB total, lifetime-packed):
//   E1  @ 0        : [32768, 512] fp32 = 64 MiB   (dead after G2)
//   E2  @ 64 MiB   : [32768, 256] fp32 = 32 MiB   (dead after G3)
//   E3  @ 128 MiB  : [32768, 128] fp32 = 16 MiB   (dead after CBP)
//   CBP @ 0        : [16384,2048] fp32 = 128 MiB  (overwrites dead E1/E2)
//   Z   @ 128 MiB  : [16384,1024] fp32 = 64 MiB   (overwrites dead E3)
// ---------------------------------------------------------------------------
extern "C" void kernel_launch(void* const* d_in, const int* in_sizes, int n_in,
                              void* d_out, int out_size, void* d_ws, size_t ws_size,
                              hipStream_t stream) {
  const float* X       = (const float*)d_in[0];
  const float* Centers = (const float*)d_in[1];
  const float* W1      = (const float*)d_in[2];
  const float* b1      = (const float*)d_in[3];
  const float* W2      = (const float*)d_in[4];
  const float* b2      = (const float*)d_in[5];
  const float* W3      = (const float*)d_in[6];
  const float* b3      = (const float*)d_in[7];
  const int*   h1      = (const int*)d_in[8];
  const float* s1      = (const float*)d_in[9];
  const int*   h2      = (const int*)d_in[10];
  const float* s2      = (const float*)d_in[11];
  const float* Wc1     = (const float*)d_in[12];
  const float* bc1     = (const float*)d_in[13];
  const float* Wc2     = (const float*)d_in[14];
  const float* bc2     = (const float*)d_in[15];
  float* out = (float*)d_out;

  char* ws = (char*)d_ws;
  float* E1  = (float*)(ws);
  float* E2  = (float*)(ws + (size_t)64 * 1024 * 1024);
  float* E3  = (float*)(ws + (size_t)128 * 1024 * 1024);
  float* CBP = (float*)(ws);
  float* Z   = (float*)(ws + (size_t)128 * 1024 * 1024);

  const dim3 blk(256);

  // G1: X / Centers -> E1 [32768, 512], K=1024
  gemm_bias_lrelu<<<dim3(H1_DIM / BN, BATCH / BM), blk, 0, stream>>>(
      X, W1, b1, E1, BATCH, H1_DIM, D_IN);
  gemm_bias_lrelu<<<dim3(H1_DIM / BN, BATCH / BM), blk, 0, stream>>>(
      Centers, W1, b1, E1 + (size_t)BATCH * H1_DIM, BATCH, H1_DIM, D_IN);

  // G2: E1 -> E2 [32768, 256], K=512
  gemm_bias_lrelu<<<dim3(H2_DIM / BN, 2 * BATCH / BM), blk, 0, stream>>>(
      E1, W2, b2, E2, 2 * BATCH, H2_DIM, H1_DIM);

  // G3: E2 -> E3 [32768, 128], K=256
  gemm_bias_lrelu<<<dim3(H3_DIM / BN, 2 * BATCH / BM), blk, 0, stream>>>(
      E2, W3, b3, E3, 2 * BATCH, H3_DIM, H2_DIM);

  // CBP: E3 -> CBP [16384, 2048]
  cbp_kernel<<<dim3(BATCH), blk, 0, stream>>>(E3, h1, s1, h2, s2, CBP);

  // G4: CBP -> Z [16384, 1024], K=2048
  gemm_bias_lrelu<<<dim3(H_C / BN, BATCH / BM), blk, 0, stream>>>(
      CBP, Wc1, bc1, Z, BATCH, H_C, D_CBP);

  // G5 + softmax: Z -> out [16384, 10]
  head_softmax<<<dim3(BATCH / 4), blk, 0, stream>>>(Z, Wc2, bc2, out);
}

// Round 2
// 1956.152 us; speedup vs baseline: 1.6806x; 1.6806x over previous
//
#include <hip/hip_runtime.h>
#include <hip/hip_bf16.h>
#include <math.h>

// ---------------------------------------------------------------------------
// Dims (fixed per reference)
// ---------------------------------------------------------------------------
#define BATCH   16384
#define D_IN    1024
#define H1_DIM  512
#define H2_DIM  256
#define H3_DIM  128
#define D_CBP   2048
#define H_C     1024
#define CLASSES 10
#define SLOPE   0.2f

// ---------------------------------------------------------------------------
// fp32 GEMM: C[M,N] = lrelu(A[M,K] @ W[K,N] + bias[N])
// BM=BN=128, BK=8, 256 threads, 8x8 micro-tile.
// A-tile transposed in LDS (pad to 132 for alignment+banks);
// B-tile XOR-swizzled on 16B granules to kill the tx*32B 4-way conflict.
// M,N multiples of 128; K multiple of 8 (true at all call sites).
// ---------------------------------------------------------------------------
#define BM 128
#define BN 128
#define BK 8

__device__ __forceinline__ int swz(int g) { return g ^ ((g >> 3) << 1); }

__global__ __launch_bounds__(256, 2) void gemm_bias_lrelu(
    const float* __restrict__ A, const float* __restrict__ W,
    const float* __restrict__ bias, float* __restrict__ C,
    int M, int N, int K)
{
  __shared__ __align__(16) float  As[BK][BM + 4];   // [k][m], stride 132 (16B-aligned rows)
  __shared__ float4 Bs4[BK * 32];                   // [k][granule], XOR-swizzled

  const int tid = threadIdx.x;
  const int tx  = tid & 15;       // n-direction, owns cols tx*8..tx*8+7
  const int ty  = tid >> 4;       // m-direction, owns rows ty*8..ty*8+7
  const int m0  = blockIdx.y * BM;
  const int n0  = blockIdx.x * BN;

  // staging assignment
  const int am = tid >> 1;              // 0..127
  const int ak = (tid & 1) << 2;        // 0 or 4
  const int bk = tid >> 5;              // 0..7
  const int bg = tid & 31;              // B granule (16B) within row

  const float* Ag = A + (size_t)(m0 + am) * K + ak;
  const float* Wg = W + (size_t)bk * N + n0 + (bg << 2);

  const int g0 = swz(2 * tx);           // swizzled read granules (hoisted)
  const int g1 = swz(2 * tx + 1);
  const int bs_w = bk * 32 + swz(bg);   // swizzled write slot

  float acc[8][8];
#pragma unroll
  for (int i = 0; i < 8; ++i)
#pragma unroll
    for (int j = 0; j < 8; ++j) acc[i][j] = 0.f;

  for (int k0 = 0; k0 < K; k0 += BK) {
    const float4 av = *(const float4*)(Ag + k0);
    const float4 bv = *(const float4*)(Wg + (size_t)k0 * N);
    __syncthreads();                 // protect previous iteration's reads
    As[ak + 0][am] = av.x;
    As[ak + 1][am] = av.y;
    As[ak + 2][am] = av.z;
    As[ak + 3][am] = av.w;
    Bs4[bs_w] = bv;
    __syncthreads();
#pragma unroll
    for (int kk = 0; kk < BK; ++kk) {
      float a[8], b[8];
      *(float4*)&a[0] = *(const float4*)&As[kk][ty * 8];
      *(float4*)&a[4] = *(const float4*)&As[kk][ty * 8 + 4];
      *(float4*)&b[0] = Bs4[kk * 32 + g0];
      *(float4*)&b[4] = Bs4[kk * 32 + g1];
#pragma unroll
      for (int i = 0; i < 8; ++i)
#pragma unroll
        for (int j = 0; j < 8; ++j) acc[i][j] += a[i] * b[j];
    }
  }

  const float4 bb0 = *(const float4*)(bias + n0 + tx * 8);
  const float4 bb1 = *(const float4*)(bias + n0 + tx * 8 + 4);
#pragma unroll
  for (int i = 0; i < 8; ++i) {
    float4 v0, v1;
    v0.x = acc[i][0] + bb0.x; v0.y = acc[i][1] + bb0.y;
    v0.z = acc[i][2] + bb0.z; v0.w = acc[i][3] + bb0.w;
    v1.x = acc[i][4] + bb1.x; v1.y = acc[i][5] + bb1.y;
    v1.z = acc[i][6] + bb1.z; v1.w = acc[i][7] + bb1.w;
    v0.x = v0.x >= 0.f ? v0.x : SLOPE * v0.x;
    v0.y = v0.y >= 0.f ? v0.y : SLOPE * v0.y;
    v0.z = v0.z >= 0.f ? v0.z : SLOPE * v0.z;
    v0.w = v0.w >= 0.f ? v0.w : SLOPE * v0.w;
    v1.x = v1.x >= 0.f ? v1.x : SLOPE * v1.x;
    v1.y = v1.y >= 0.f ? v1.y : SLOPE * v1.y;
    v1.z = v1.z >= 0.f ? v1.z : SLOPE * v1.z;
    v1.w = v1.w >= 0.f ? v1.w : SLOPE * v1.w;
    float* Crow = C + (size_t)(m0 + ty * 8 + i) * N + n0 + tx * 8;
    *(float4*)(Crow)     = v0;
    *(float4*)(Crow + 4) = v1;
  }
}

// ---------------------------------------------------------------------------
// Compact bilinear pooling — GATHER formulation (no hot-path atomics):
//   bsk[q]   = sum_j s2[j]*ec[b,j] * [h2[j]==q]      (128-elem scatter, cheap)
//   cbp[b,k] = sum_i (s1[i]*ex[b,i]) * bsk[(k - h1[i]) mod 2048]
// bsk duplicated to 4096 entries so (base + 256*r) never needs a mask.
// Lanes gather consecutive addresses -> 2 lanes/bank = conflict-free.
// a_i / h1_i broadcast via v_readlane (no LDS traffic).
// ---------------------------------------------------------------------------
__global__ __launch_bounds__(256) void cbp_kernel(
    const float* __restrict__ E3,   // [2*BATCH, 128]: rows 0..B-1 = ex, B.. = ec
    const int*   __restrict__ h1, const float* __restrict__ s1,
    const int*   __restrict__ h2, const float* __restrict__ s2,
    float* __restrict__ cbp)        // [BATCH, 2048]
{
  __shared__ float bsk2[2 * D_CBP];

  const int b    = blockIdx.x;
  const int t    = threadIdx.x;
  const int lane = t & 63;

#pragma unroll
  for (int q = 0; q < D_CBP; q += 256) bsk2[q + t] = 0.f;

  // a-side values + hashes into registers (each wave holds the full 128)
  const float va0 = E3[(size_t)b * H3_DIM + lane]      * s1[lane];
  const float va1 = E3[(size_t)b * H3_DIM + 64 + lane] * s1[64 + lane];
  const int   vh0 = h1[lane];
  const int   vh1 = h1[64 + lane];

  __syncthreads();
  if (t < H3_DIM) {
    const float bv = E3[(size_t)(BATCH + b) * H3_DIM + t] * s2[t];
    atomicAdd(&bsk2[h2[t]], bv);   // 128 ops, ~no contention: CAS cost negligible
  }
  __syncthreads();
#pragma unroll
  for (int q = 0; q < D_CBP; q += 256) bsk2[D_CBP + q + t] = bsk2[q + t];
  __syncthreads();

  float acc[8];
#pragma unroll
  for (int r = 0; r < 8; ++r) acc[r] = 0.f;

#pragma unroll 8
  for (int i = 0; i < 64; ++i) {
    const int   hi = __builtin_amdgcn_readlane(vh0, i);
    const float ai = __uint_as_float(
        __builtin_amdgcn_readlane(__float_as_uint(va0), i));
    const int base = (t - hi) & (D_CBP - 1);
#pragma unroll
    for (int r = 0; r < 8; ++r) acc[r] += ai * bsk2[base + 256 * r];
  }
#pragma unroll 8
  for (int i = 0; i < 64; ++i) {
    const int   hi = __builtin_amdgcn_readlane(vh1, i);
    const float ai = __uint_as_float(
        __builtin_amdgcn_readlane(__float_as_uint(va1), i));
    const int base = (t - hi) & (D_CBP - 1);
#pragma unroll
    for (int r = 0; r < 8; ++r) acc[r] += ai * bsk2[base + 256 * r];
  }

  float* dst = cbp + (size_t)b * D_CBP + t;
#pragma unroll
  for (int r = 0; r < 8; ++r) dst[256 * r] = acc[r];
}

// ---------------------------------------------------------------------------
// Head: logits = Z[B,1024] @ Wc2[1024,10] + bc2; out = softmax(logits).
// One wave per row (4 rows / 256-thread block); shuffle reduction.
// ---------------------------------------------------------------------------
__global__ __launch_bounds__(256) void head_softmax(
    const float* __restrict__ Z, const float* __restrict__ Wc2,
    const float* __restrict__ bc2, float* __restrict__ out)
{
  const int row  = blockIdx.x * 4 + (threadIdx.x >> 6);
  const int lane = threadIdx.x & 63;

  float acc[CLASSES];
#pragma unroll
  for (int c = 0; c < CLASSES; ++c) acc[c] = 0.f;

  const float* z = Z + (size_t)row * H_C;
  for (int k = lane; k < H_C; k += 64) {
    const float zv = z[k];
    const float* w = Wc2 + (size_t)k * CLASSES;
#pragma unroll
    for (int c = 0; c < CLASSES; ++c) acc[c] += zv * w[c];
  }
#pragma unroll
  for (int c = 0; c < CLASSES; ++c) {
#pragma unroll
    for (int off = 32; off > 0; off >>= 1)
      acc[c] += __shfl_down(acc[c], off);
  }
  if (lane == 0) {
    float l[CLASSES], mx = -1e30f;
#pragma unroll
    for (int c = 0; c < CLASSES; ++c) { l[c] = acc[c] + bc2[c]; mx = fmaxf(mx, l[c]); }
    float s = 0.f;
#pragma unroll
    for (int c = 0; c < CLASSES; ++c) { l[c] = __expf(l[c] - mx); s += l[c]; }
    const float inv = 1.f / s;
#pragma unroll
    for (int c = 0; c < CLASSES; ++c) out[(size_t)row * CLASSES + c] = l[c] * inv;
  }
}

// ---------------------------------------------------------------------------
// Launcher. Workspace layout (192 MiB total, lifetime-packed):
//   E1  @ 0        : [32768, 512] fp32 = 64 MiB   (dead after G2)
//   E2  @ 64 MiB   : [32768, 256] fp32 = 32 MiB   (dead after G3)
//   E3  @ 128 MiB  : [32768, 128] fp32 = 16 MiB   (dead after CBP)
//   CBP @ 0        : [16384,2048] fp32 = 128 MiB  (overwrites dead E1/E2)
//   Z   @ 128 MiB  : [16384,1024] fp32 = 64 MiB   (overwrites dead E3)
// ---------------------------------------------------------------------------
extern "C" void kernel_launch(void* const* d_in, const int* in_sizes, int n_in,
                              void* d_out, int out_size, void* d_ws, size_t ws_size,
                              hipStream_t stream) {
  const float* X       = (const float*)d_in[0];
  const float* Centers = (const float*)d_in[1];
  const float* W1      = (const float*)d_in[2];
  const float* b1      = (const float*)d_in[3];
  const float* W2      = (const float*)d_in[4];
  const float* b2      = (const float*)d_in[5];
  const float* W3      = (const float*)d_in[6];
  const float* b3      = (const float*)d_in[7];
  const int*   h1      = (const int*)d_in[8];
  const float* s1      = (const float*)d_in[9];
  const int*   h2      = (const int*)d_in[10];
  const float* s2      = (const float*)d_in[11];
  const float* Wc1     = (const float*)d_in[12];
  const float* bc1     = (const float*)d_in[13];
  const float* Wc2     = (const float*)d_in[14];
  const float* bc2     = (const float*)d_in[15];
  float* out = (float*)d_out;

  char* ws = (char*)d_ws;
  float* E1  = (float*)(ws);
  float* E2  = (float*)(ws + (size_t)64 * 1024 * 1024);
  float* E3  = (float*)(ws + (size_t)128 * 1024 * 1024);
  float* CBP = (float*)(ws);
  float* Z   = (float*)(ws + (size_t)128 * 1024 * 1024);

  const dim3 blk(256);

  // G1: X / Centers -> E1 [32768, 512], K=1024
  gemm_bias_lrelu<<<dim3(H1_DIM / BN, BATCH / BM), blk, 0, stream>>>(
      X, W1, b1, E1, BATCH, H1_DIM, D_IN);
  gemm_bias_lrelu<<<dim3(H1_DIM / BN, BATCH / BM), blk, 0, stream>>>(
      Centers, W1, b1, E1 + (size_t)BATCH * H1_DIM, BATCH, H1_DIM, D_IN);

  // G2: E1 -> E2 [32768, 256], K=512
  gemm_bias_lrelu<<<dim3(H2_DIM / BN, 2 * BATCH / BM), blk, 0, stream>>>(
      E1, W2, b2, E2, 2 * BATCH, H2_DIM, H1_DIM);

  // G3: E2 -> E3 [32768, 128], K=256
  gemm_bias_lrelu<<<dim3(H3_DIM / BN, 2 * BATCH / BM), blk, 0, stream>>>(
      E2, W3, b3, E3, 2 * BATCH, H3_DIM, H2_DIM);

  // CBP: E3 -> CBP [16384, 2048]
  cbp_kernel<<<dim3(BATCH), blk, 0, stream>>>(E3, h1, s1, h2, s2, CBP);

  // G4: CBP -> Z [16384, 1024], K=2048
  gemm_bias_lrelu<<<dim3(H_C / BN, BATCH / BM), blk, 0, stream>>>(
      CBP, Wc1, bc1, Z, BATCH, H_C, D_CBP);

  // G5 + softmax: Z -> out [16384, 10]
  head_softmax<<<dim3(BATCH / 4), blk, 0, stream>>>(Z, Wc2, bc2, out);
}

// Round 3
// 727.158 us; speedup vs baseline: 4.5211x; 2.6901x over previous
//
#include <hip/hip_runtime.h>
#include <hip/hip_bf16.h>
#include <math.h>

// ---------------------------------------------------------------------------
// Dims (fixed per reference)
// ---------------------------------------------------------------------------
#define BATCH   16384
#define D_IN    1024
#define H1_DIM  512
#define H2_DIM  256
#define H3_DIM  128
#define D_CBP   2048
#define H_C     1024
#define CLASSES 10
#define SLOPE   0.2f

typedef short v8s __attribute__((ext_vector_type(8)));
typedef float v4f __attribute__((ext_vector_type(4)));
typedef unsigned short u16;

__device__ __forceinline__ float b2f(unsigned short u) {
  return __uint_as_float(((unsigned)u) << 16);
}
__device__ __forceinline__ u16 f2b(float f) {
  __hip_bfloat16 h = __float2bfloat16(f);   // RNE
  return __builtin_bit_cast(unsigned short, h);
}

// async 16B global->LDS (direct-to-shared DMA). LDS dest = wave-uniform base
// + lane*16 (guide m104/m108) -> LDS layout is forced packed lane-order.
__device__ __forceinline__ void g2l16(const void* g, void* l) {
  __builtin_amdgcn_global_load_lds(
      (const __attribute__((address_space(1))) void*)g,
      (__attribute__((address_space(3))) void*)l, 16, 0, 0);
}

// ---------------------------------------------------------------------------
// bf16 MFMA GEMM (m97 structure): C[M,N] = lrelu(A[M,K] @ Bt[N,K]^T + bias)
// Tile 128x128, BK=32, 256 threads (4 waves, 2x2 of 64x64), 16 MFMA/wave/step.
// Granule rotation swizzle: within each LDS row (32 bf16 = 4x16B granules),
// logical granule g is stored at phys (g + (row>>1))&3 — applied on the
// GLOBAL address at staging (LDS side is fixed by global_load_lds). This
// makes both A- and B-fragment ds_read_b128 exactly 2 lanes/bank (free).
// M,N mult of 128; K mult of 32.
// ---------------------------------------------------------------------------
__global__ __launch_bounds__(256) void gemm_bf16(
    const u16* __restrict__ A,   // [M][K] bf16
    const u16* __restrict__ Bt,  // [N][K] bf16  (weights pre-transposed)
    const float* __restrict__ bias,
    u16* __restrict__ C,         // [M][N] bf16
    int M, int N, int K)
{
  __shared__ __align__(16) short Asb[128 * 32];
  __shared__ __align__(16) short Bsb[128 * 32];

  const int tid  = threadIdx.x;
  const int wave = tid >> 6, lane = tid & 63;
  const int wm = wave >> 1, wn = wave & 1;
  const int u = lane & 15, quad = lane >> 4;
  const int m0 = blockIdx.y * 128, n0 = blockIdx.x * 128;

  // ---- staging addresses (each wave stages 32 rows of A and of Bt) ----
  // lane covers (row = base + lane>>2, phys granule = lane&3); the global
  // column granule it must fetch is the inverse rotation:
  const int g_log = ((lane & 3) - ((lane >> 3) & 3)) & 3;
  const int srow  = wave * 32 + (lane >> 2);
  const u16* gA0 = A  + (size_t)(m0 + srow)      * K + g_log * 8;
  const u16* gA1 = A  + (size_t)(m0 + srow + 16) * K + g_log * 8;
  const u16* gB0 = Bt + (size_t)(n0 + srow)      * K + g_log * 8;
  const u16* gB1 = Bt + (size_t)(n0 + srow + 16) * K + g_log * 8;
  short* lA0 = &Asb[(wave * 32)      * 32];
  short* lA1 = &Asb[(wave * 32 + 16) * 32];
  short* lB0 = &Bsb[(wave * 32)      * 32];
  short* lB1 = &Bsb[(wave * 32 + 16) * 32];

  // ---- fragment read offsets (K-invariant, rotated granule) ----
  const int gran = (quad + (u >> 1)) & 3;
  int offA[4], offB[4];
#pragma unroll
  for (int i = 0; i < 4; ++i) {
    offA[i] = (wm * 64 + i * 16 + u) * 32 + gran * 8;
    offB[i] = (wn * 64 + i * 16 + u) * 32 + gran * 8;
  }

  v4f acc[4][4];
#pragma unroll
  for (int i = 0; i < 4; ++i)
#pragma unroll
    for (int j = 0; j < 4; ++j) acc[i][j] = (v4f){0.f, 0.f, 0.f, 0.f};

  for (int k0 = 0; k0 < K; k0 += 32) {
    __syncthreads();               // prev iteration's ds_reads done
    g2l16(gA0 + k0, lA0);
    g2l16(gA1 + k0, lA1);
    g2l16(gB0 + k0, lB0);
    g2l16(gB1 + k0, lB1);
    __syncthreads();               // drains vmcnt -> staged data visible
    v8s a[4], b[4];
#pragma unroll
    for (int i = 0; i < 4; ++i) a[i] = *(const v8s*)&Asb[offA[i]];
#pragma unroll
    for (int j = 0; j < 4; ++j) b[j] = *(const v8s*)&Bsb[offB[j]];
#pragma unroll
    for (int i = 0; i < 4; ++i)
#pragma unroll
      for (int j = 0; j < 4; ++j)
        acc[i][j] = __builtin_amdgcn_mfma_f32_16x16x32_bf16(a[i], b[j], acc[i][j], 0, 0, 0);
  }

  // ---- epilogue: bias + lrelu + bf16 store ----
  // C/D layout (m89-verified): col = lane&15, row = quad*4 + reg
  float bcol[4];
#pragma unroll
  for (int j = 0; j < 4; ++j) bcol[j] = bias[n0 + wn * 64 + j * 16 + u];
#pragma unroll
  for (int i = 0; i < 4; ++i)
#pragma unroll
    for (int r = 0; r < 4; ++r) {
      const size_t ro = (size_t)(m0 + wm * 64 + i * 16 + quad * 4 + r) * N
                        + n0 + wn * 64 + u;
#pragma unroll
      for (int j = 0; j < 4; ++j) {
        float v = acc[i][j][r] + bcol[j];
        v = v >= 0.f ? v : SLOPE * v;
        C[ro + j * 16] = f2b(v);
      }
    }
}

// ---------------------------------------------------------------------------
// cast fp32 -> bf16 (float4 in, 4x bf16 out)
// ---------------------------------------------------------------------------
__global__ __launch_bounds__(256) void cast_bf16(
    const float* __restrict__ src, u16* __restrict__ dst, int n4)
{
  const int i = blockIdx.x * 256 + threadIdx.x;
  if (i < n4) {
    const float4 v = ((const float4*)src)[i];
    __align__(8) u16 o[4] = {f2b(v.x), f2b(v.y), f2b(v.z), f2b(v.w)};
    *(uint2*)(dst + (size_t)i * 4) = *(uint2*)o;
  }
}

// ---------------------------------------------------------------------------
// transpose + cast: W[K][N] fp32 -> Wt[N][K] bf16.  32x32 tiles via LDS.
// ---------------------------------------------------------------------------
__global__ __launch_bounds__(256) void transpose_cast(
    const float* __restrict__ W, u16* __restrict__ Wt, int K, int N)
{
  __shared__ float tile[32][33];
  const int k0 = blockIdx.x * 32, n0 = blockIdx.y * 32;
  const int tx = threadIdx.x & 31, ty = threadIdx.x >> 5;
#pragma unroll
  for (int s = 0; s < 4; ++s) {
    const int k = ty * 4 + s;
    tile[k][tx] = W[(size_t)(k0 + k) * N + n0 + tx];
  }
  __syncthreads();
#pragma unroll
  for (int s = 0; s < 4; ++s) {
    const int n = ty * 4 + s;
    Wt[(size_t)(n0 + n) * K + k0 + tx] = f2b(tile[tx][n]);
  }
}

// ---------------------------------------------------------------------------
// Compact bilinear pooling, gather form with 8 rotated bf16 LDS copies:
//   bsk[q]    = sum_j s2[j]*ec[b,j]*[h2[j]==q]
//   rot_r[q]  = bf16(bsk[(q-r) & 2047])        r = 0..7   (32 KiB LDS)
//   cbp[b,k]  = sum_i a_i * bsk[(k - h1_i) & 2047],  a_i = s1[i]*ex[b,i]
// Thread t owns k = 8t..8t+7. With h1_i = 8h + r the window is granule
// (t-h)&255 of rot_r -> one aligned ds_read_b128 per i (8 outputs/read).
// a_i / h1_i broadcast via readlane (zero LDS traffic).
// ---------------------------------------------------------------------------
__global__ __launch_bounds__(256) void cbp_kernel(
    const u16* __restrict__ E3,     // [2*BATCH][128] bf16
    const int* __restrict__ h1, const float* __restrict__ s1,
    const int* __restrict__ h2, const float* __restrict__ s2,
    u16* __restrict__ cbp)          // [BATCH][2048] bf16
{
  __shared__ float bsk[D_CBP];
  __shared__ __align__(16) short rot[8][D_CBP];

  const int b = blockIdx.x, t = threadIdx.x, lane = t & 63;

  for (int q = t; q < D_CBP; q += 256) bsk[q] = 0.f;

  const float va0 = b2f(E3[(size_t)b * H3_DIM + lane])      * s1[lane];
  const float va1 = b2f(E3[(size_t)b * H3_DIM + 64 + lane]) * s1[64 + lane];
  const int   vh0 = h1[lane];
  const int   vh1 = h1[64 + lane];

  __syncthreads();
  if (t < H3_DIM) {
    const float bv = b2f(E3[(size_t)(BATCH + b) * H3_DIM + t]) * s2[t];
    atomicAdd(&bsk[h2[t]], bv);     // 128 adds, negligible contention
  }
  __syncthreads();
  for (int x = t; x < 8 * D_CBP; x += 256) {
    const int r = x >> 11, q = x & (D_CBP - 1);
    rot[r][q] = (short)f2b(bsk[(q - r) & (D_CBP - 1)]);
  }
  __syncthreads();

  float acc[8];
#pragma unroll
  for (int c = 0; c < 8; ++c) acc[c] = 0.f;

#pragma unroll
  for (int i = 0; i < 64; ++i) {
    const int   hi = __builtin_amdgcn_readlane(vh0, i);
    const float ai = __uint_as_float(
        __builtin_amdgcn_readlane(__float_as_uint(va0), i));
    const int g = (t - (hi >> 3)) & 255;
    const v8s v = *(const v8s*)&rot[hi & 7][g * 8];
#pragma unroll
    for (int c = 0; c < 8; ++c) acc[c] += ai * b2f((u16)v[c]);
  }
#pragma unroll
  for (int i = 0; i < 64; ++i) {
    const int   hi = __builtin_amdgcn_readlane(vh1, i);
    const float ai = __uint_as_float(
        __builtin_amdgcn_readlane(__float_as_uint(va1), i));
    const int g = (t - (hi >> 3)) & 255;
    const v8s v = *(const v8s*)&rot[hi & 7][g * 8];
#pragma unroll
    for (int c = 0; c < 8; ++c) acc[c] += ai * b2f((u16)v[c]);
  }

  v8s ov;
#pragma unroll
  for (int c = 0; c < 8; ++c) ov[c] = (short)f2b(acc[c]);
  *(v8s*)(cbp + (size_t)b * D_CBP + t * 8) = ov;
}

// ---------------------------------------------------------------------------
// Head: logits = Z[B,1024](bf16) @ Wc2[1024,10] + bc2; softmax -> fp32 out.
// ---------------------------------------------------------------------------
__global__ __launch_bounds__(256) void head_softmax(
    const u16* __restrict__ Z, const float* __restrict__ Wc2,
    const float* __restrict__ bc2, float* __restrict__ out)
{
  const int row  = blockIdx.x * 4 + (threadIdx.x >> 6);
  const int lane = threadIdx.x & 63;

  float acc[CLASSES];
#pragma unroll
  for (int c = 0; c < CLASSES; ++c) acc[c] = 0.f;

  const u16* z = Z + (size_t)row * H_C;
  for (int k = lane; k < H_C; k += 64) {
    const float zv = b2f(z[k]);
    const float* w = Wc2 + (size_t)k * CLASSES;
#pragma unroll
    for (int c = 0; c < CLASSES; ++c) acc[c] += zv * w[c];
  }
#pragma unroll
  for (int c = 0; c < CLASSES; ++c) {
#pragma unroll
    for (int off = 32; off > 0; off >>= 1)
      acc[c] += __shfl_down(acc[c], off);
  }
  if (lane == 0) {
    float l[CLASSES], mx = -1e30f;
#pragma unroll
    for (int c = 0; c < CLASSES; ++c) { l[c] = acc[c] + bc2[c]; mx = fmaxf(mx, l[c]); }
    float s = 0.f;
#pragma unroll
    for (int c = 0; c < CLASSES; ++c) { l[c] = __expf(l[c] - mx); s += l[c]; }
    const float inv = 1.f / s;
#pragma unroll
    for (int c = 0; c < CLASSES; ++c) out[(size_t)row * CLASSES + c] = l[c] * inv;
  }
}

// ---------------------------------------------------------------------------
// Launcher.  Workspace (bytes, 1 MiB = 1<<20), lifetime-packed, 126 MiB:
//   Xb   @ 0       [32768,1024] bf16 = 64 MiB   (dead after G1)
//   CBPb @ 0       [16384,2048] bf16 = 64 MiB   (overlays Xb)
//   E1b  @ 64 MiB  [32768, 512] bf16 = 32 MiB   (dead after G2)
//   Zb   @ 64 MiB  [16384,1024] bf16 = 32 MiB   (overlays E1b)
//   E2b  @ 96 MiB  [32768, 256] bf16 = 16 MiB
//   E3b  @ 112 MiB [32768, 128] bf16 =  8 MiB
//   W1t @120M  W2t @121M  W3t @121.5M  Wc1t @122M..126M (bf16, transposed)
// ---------------------------------------------------------------------------
extern "C" void kernel_launch(void* const* d_in, const int* in_sizes, int n_in,
                              void* d_out, int out_size, void* d_ws, size_t ws_size,
                              hipStream_t stream) {
  const float* X       = (const float*)d_in[0];
  const float* Centers = (const float*)d_in[1];
  const float* W1      = (const float*)d_in[2];
  const float* b1      = (const float*)d_in[3];
  const float* W2      = (const float*)d_in[4];
  const float* b2      = (const float*)d_in[5];
  const float* W3      = (const float*)d_in[6];
  const float* b3      = (const float*)d_in[7];
  const int*   h1      = (const int*)d_in[8];
  const float* s1      = (const float*)d_in[9];
  const int*   h2      = (const int*)d_in[10];
  const float* s2      = (const float*)d_in[11];
  const float* Wc1     = (const float*)d_in[12];
  const float* bc1     = (const float*)d_in[13];
  const float* Wc2     = (const float*)d_in[14];
  const float* bc2     = (const float*)d_in[15];
  float* out = (float*)d_out;

  char* ws = (char*)d_ws;
  const size_t MB = 1u << 20;
  u16* Xb   = (u16*)(ws);
  u16* CBPb = (u16*)(ws);
  u16* E1b  = (u16*)(ws + 64 * MB);
  u16* Zb   = (u16*)(ws + 64 * MB);
  u16* E2b  = (u16*)(ws + 96 * MB);
  u16* E3b  = (u16*)(ws + 112 * MB);
  u16* W1t  = (u16*)(ws + 120 * MB);
  u16* W2t  = (u16*)(ws + 121 * MB);
  u16* W3t  = (u16*)(ws + 121 * MB + 512 * 1024);
  u16* Wc1t = (u16*)(ws + 122 * MB);

  const dim3 blk(256);

  // casts: X, Centers -> Xb rows [0..B), [B..2B)
  cast_bf16<<<dim3((BATCH * D_IN / 4 + 255) / 256), blk, 0, stream>>>(
      X, Xb, BATCH * D_IN / 4);
  cast_bf16<<<dim3((BATCH * D_IN / 4 + 255) / 256), blk, 0, stream>>>(
      Centers, Xb + (size_t)BATCH * D_IN, BATCH * D_IN / 4);

  // weight transposes
  transpose_cast<<<dim3(D_IN / 32, H1_DIM / 32), blk, 0, stream>>>(W1, W1t, D_IN, H1_DIM);
  transpose_cast<<<dim3(H1_DIM / 32, H2_DIM / 32), blk, 0, stream>>>(W2, W2t, H1_DIM, H2_DIM);
  transpose_cast<<<dim3(H2_DIM / 32, H3_DIM / 32), blk, 0, stream>>>(W3, W3t, H2_DIM, H3_DIM);
  transpose_cast<<<dim3(D_CBP / 32, H_C / 32), blk, 0, stream>>>(Wc1, Wc1t, D_CBP, H_C);

  // G1: [32768,1024] @ [1024,512] -> E1b
  gemm_bf16<<<dim3(H1_DIM / 128, 2 * BATCH / 128), blk, 0, stream>>>(
      Xb, W1t, b1, E1b, 2 * BATCH, H1_DIM, D_IN);
  // G2: -> E2b [32768,256]
  gemm_bf16<<<dim3(H2_DIM / 128, 2 * BATCH / 128), blk, 0, stream>>>(
      E1b, W2t, b2, E2b, 2 * BATCH, H2_DIM, H1_DIM);
  // G3: -> E3b [32768,128]
  gemm_bf16<<<dim3(H3_DIM / 128, 2 * BATCH / 128), blk, 0, stream>>>(
      E2b, W3t, b3, E3b, 2 * BATCH, H3_DIM, H2_DIM);

  // CBP: E3b -> CBPb [16384,2048]
  cbp_kernel<<<dim3(BATCH), blk, 0, stream>>>(E3b, h1, s1, h2, s2, CBPb);

  // G4: CBPb @ Wc1 -> Zb [16384,1024]
  gemm_bf16<<<dim3(H_C / 128, BATCH / 128), blk, 0, stream>>>(
      CBPb, Wc1t, bc1, Zb, BATCH, H_C, D_CBP);

  // head
  head_softmax<<<dim3(BATCH / 4), blk, 0, stream>>>(Zb, Wc2, bc2, out);
}